// Round 5
// baseline (158.587 us; speedup 1.0000x reference)
//
#include <hip/hip_runtime.h>

#define F_DIM 256
#define H 5
#define C 7
#define PAD 8

#define PART_SH 9
#define PART_NODES 512
#define PCAP 20480
#define TILE 2048
#define NPMAX 256

// Pass 1: partition edges by dst>>9. 512 threads, wave-private histograms,
// single-wave shuffle scan, per-wave reorder cursors, coalesced chunk flush.
__global__ __launch_bounds__(512) void k_part(const int* __restrict__ src,
                                              const int* __restrict__ dst,
                                              int* __restrict__ gcur,
                                              unsigned int* __restrict__ parr, int E) {
    __shared__ unsigned int s_pair[TILE];
    __shared__ unsigned char s_pp[TILE];
    __shared__ unsigned int s_out[TILE];
    __shared__ unsigned char s_op[TILE];
    __shared__ int s_wcur[8][NPMAX];   // wave-private hist, later cursors
    __shared__ int s_hist[NPMAX];
    __shared__ int s_excl[NPMAX];
    __shared__ int s_gbase[NPMAX];

    const int t = threadIdx.x;
    const int w = t >> 6;
    const int t0 = blockIdx.x * TILE;

    for (int i = t; i < 8 * NPMAX; i += 512) ((int*)s_wcur)[i] = 0;
    __syncthreads();

#pragma unroll
    for (int k = 0; k < 4; ++k) {
        int i = k * 512 + t;
        int e = t0 + i;
        if (e < E) {
            int d = dst[e];
            int s = src[e];
            int p = d >> PART_SH;
            s_pair[i] = ((unsigned)s << PART_SH) | (unsigned)(d & (PART_NODES - 1));
            s_pp[i] = (unsigned char)p;
            atomicAdd(&s_wcur[w][p], 1);
        } else {
            s_pp[i] = 0;
        }
    }
    __syncthreads();
    if (t < NPMAX) {
        int sum = 0;
#pragma unroll
        for (int ww = 0; ww < 8; ++ww) sum += s_wcur[ww][t];
        s_hist[t] = sum;
    }
    __syncthreads();
    if (t < 64) {
        int base = t * 4;
        int loc[4]; int tot = 0;
#pragma unroll
        for (int k = 0; k < 4; ++k) { loc[k] = tot; tot += s_hist[base + k]; }
        int incl = tot;
#pragma unroll
        for (int off = 1; off < 64; off <<= 1) {
            int u = __shfl_up(incl, off, 64);
            if (t >= off) incl += u;
        }
        int excl = incl - tot;
#pragma unroll
        for (int k = 0; k < 4; ++k) s_excl[base + k] = excl + loc[k];
    }
    __syncthreads();
    if (t < NPMAX) {
        int run = s_excl[t];
#pragma unroll
        for (int ww = 0; ww < 8; ++ww) { int c = s_wcur[ww][t]; s_wcur[ww][t] = run; run += c; }
        int cnt = s_hist[t];
        s_gbase[t] = (cnt > 0) ? atomicAdd(&gcur[t], cnt) : 0;
    }
    __syncthreads();
#pragma unroll
    for (int k = 0; k < 4; ++k) {
        int i = k * 512 + t;
        int e = t0 + i;
        if (e < E) {
            int p = s_pp[i];
            int pos = atomicAdd(&s_wcur[w][p], 1);   // wave-local contention only
            s_out[pos] = s_pair[i];
            s_op[pos] = (unsigned char)p;
        }
    }
    __syncthreads();
    const int tilecnt = s_excl[NPMAX - 1] + s_hist[NPMAX - 1];
#pragma unroll
    for (int k = 0; k < 4; ++k) {
        int i = k * 512 + t;
        if (i < tilecnt) {
            int p = s_op[i];
            int gpos = s_gbase[p] + (i - s_excl[p]);
            if (gpos < PCAP)
                parr[(size_t)p * PCAP + gpos] = s_out[i];
        }
    }
}

// Pass 2 fused: blocks [0,np) build per-partition CSR (+deg+dis);
// blocks [np,grid) compute hw1 = x @ W1.
// xw1 structure: 4 rows per wave, 16 lanes per row; each lane covers 16
// features (4 independent float4 loads); W1 fragment (80 regs) hoisted;
// reduce = 4 butterfly levels over 16-lane groups (5 bpermutes/row).
__global__ __launch_bounds__(512) void k_csr_xw1(
        const int* __restrict__ gcur, const unsigned int* __restrict__ parr,
        int* __restrict__ sorted, int* __restrict__ row_ptr, int* __restrict__ degv,
        float* __restrict__ dis,
        const float* __restrict__ x, const float* __restrict__ W1,
        float* __restrict__ hw1, int n, int np) {
    __shared__ int s_hist[PART_NODES];
    __shared__ int s_excl[PART_NODES];
    __shared__ int s_cur[PART_NODES];
    const int t = threadIdx.x;

    if ((int)blockIdx.x < np) {
        const int p = blockIdx.x;
        int m = gcur[p]; if (m > PCAP) m = PCAP;
        const unsigned int* pp = parr + (size_t)p * PCAP;

        s_hist[t] = 0;
        __syncthreads();
        for (int i = t; i < m; i += 512)
            atomicAdd(&s_hist[pp[i] & (PART_NODES - 1)], 1);
        __syncthreads();
        if (t < 64) {
            int base = t * 8;
            int loc[8]; int tot = 0;
#pragma unroll
            for (int k = 0; k < 8; ++k) { loc[k] = tot; tot += s_hist[base + k]; }
            int incl = tot;
#pragma unroll
            for (int off = 1; off < 64; off <<= 1) {
                int u = __shfl_up(incl, off, 64);
                if (t >= off) incl += u;
            }
            int excl = incl - tot;
#pragma unroll
            for (int k = 0; k < 8; ++k) s_excl[base + k] = excl + loc[k];
        }
        __syncthreads();
        {
            int e0 = s_excl[t];
            s_cur[t] = e0;
            int node = p * PART_NODES + t;
            if (node < n) {
                row_ptr[node] = p * PCAP + e0;
                int dg = s_hist[t];
                degv[node] = dg;
                dis[node] = rsqrtf((float)dg + 1.0f);
            }
        }
        __syncthreads();
        for (int i = t; i < m; i += 512) {
            unsigned int pr = pp[i];
            int pos = atomicAdd(&s_cur[pr & (PART_NODES - 1)], 1);
            sorted[(size_t)p * PCAP + pos] = (int)(pr >> PART_SH);
        }
    } else {
        const int lane = t & 63;
        const int g = lane >> 4;          // row within 4-row group
        const int q = lane & 15;          // 16 lanes per row
        const int wid = ((int)blockIdx.x - np) * 8 + (t >> 6);
        const int nw = ((int)gridDim.x - np) * 8;

        float w[4][4][H];                 // [k][j][ch]: feature k*64+4q+j
#pragma unroll
        for (int k = 0; k < 4; ++k)
#pragma unroll
            for (int j = 0; j < 4; ++j)
#pragma unroll
                for (int ch = 0; ch < H; ++ch)
                    w[k][j][ch] = W1[(k * 64 + 4 * q + j) * H + ch];

        for (int r0 = wid * 4; r0 < n; r0 += nw * 4) {
            int row = r0 + g;
            bool valid = row < n;
            const float* xp = x + (size_t)(valid ? row : 0) * F_DIM + 4 * q;
            float4 xv0 = *(const float4*)(xp);
            float4 xv1 = *(const float4*)(xp + 64);
            float4 xv2 = *(const float4*)(xp + 128);
            float4 xv3 = *(const float4*)(xp + 192);
            float acc[H];
#pragma unroll
            for (int ch = 0; ch < H; ++ch) {
                acc[ch] = xv0.x * w[0][0][ch] + xv0.y * w[0][1][ch]
                        + xv0.z * w[0][2][ch] + xv0.w * w[0][3][ch]
                        + xv1.x * w[1][0][ch] + xv1.y * w[1][1][ch]
                        + xv1.z * w[1][2][ch] + xv1.w * w[1][3][ch]
                        + xv2.x * w[2][0][ch] + xv2.y * w[2][1][ch]
                        + xv2.z * w[2][2][ch] + xv2.w * w[2][3][ch]
                        + xv3.x * w[3][0][ch] + xv3.y * w[3][1][ch]
                        + xv3.z * w[3][2][ch] + xv3.w * w[3][3][ch];
            }
#pragma unroll
            for (int off = 1; off <= 8; off <<= 1)
#pragma unroll
                for (int ch = 0; ch < H; ++ch)
                    acc[ch] += __shfl_xor(acc[ch], off, 64);
            if (q == 0 && valid) {
                float* o = hw1 + (size_t)row * PAD;
                *reinterpret_cast<float4*>(o) = make_float4(acc[0], acc[1], acc[2], acc[3]);
                o[4] = acc[4];
            }
        }
    }
}

// Gather-aggregate (CSR) + fused epilogue. 4 lanes per node, 4-deep gather ILP.
template<int OUTD, int OSTRIDE, bool ADD_B3, bool GDIS, bool SCALE_OUT>
__global__ __launch_bounds__(256) void k_layer(
        const int* __restrict__ sorted, const int* __restrict__ row_ptr,
        const int* __restrict__ degv, const float* __restrict__ dis,
        const float* __restrict__ hin, const float* __restrict__ bn,
        const float* __restrict__ Wnext, const float* __restrict__ b3,
        float* __restrict__ outp, int n) {
    int tid = blockIdx.x * blockDim.x + threadIdx.x;
    int node = tid >> 2, sub = tid & 3;
    if (node >= n) return;
    int deg = degv[node];
    const int* bp = sorted + row_ptr[node];

    float acc[H] = {0.f, 0.f, 0.f, 0.f, 0.f};
    int j = sub;
    for (; j + 16 <= deg; j += 16) {
        int s0 = bp[j], s1 = bp[j + 4], s2 = bp[j + 8], s3 = bp[j + 12];
        const float4* h0 = (const float4*)(hin + (size_t)s0 * PAD);
        const float4* h1 = (const float4*)(hin + (size_t)s1 * PAD);
        const float4* h2 = (const float4*)(hin + (size_t)s2 * PAD);
        const float4* h3 = (const float4*)(hin + (size_t)s3 * PAD);
        float4 a0 = h0[0], e0 = h0[1], a1 = h1[0], e1 = h1[1];
        float4 a2 = h2[0], e2 = h2[1], a3 = h3[0], e3 = h3[1];
        if (GDIS) {
            float d0 = dis[s0], d1 = dis[s1], d2 = dis[s2], d3 = dis[s3];
            acc[0] += a0.x * d0 + a1.x * d1 + a2.x * d2 + a3.x * d3;
            acc[1] += a0.y * d0 + a1.y * d1 + a2.y * d2 + a3.y * d3;
            acc[2] += a0.z * d0 + a1.z * d1 + a2.z * d2 + a3.z * d3;
            acc[3] += a0.w * d0 + a1.w * d1 + a2.w * d2 + a3.w * d3;
            acc[4] += e0.x * d0 + e1.x * d1 + e2.x * d2 + e3.x * d3;
        } else {
            acc[0] += a0.x + a1.x + a2.x + a3.x;
            acc[1] += a0.y + a1.y + a2.y + a3.y;
            acc[2] += a0.z + a1.z + a2.z + a3.z;
            acc[3] += a0.w + a1.w + a2.w + a3.w;
            acc[4] += e0.x + e1.x + e2.x + e3.x;
        }
    }
    for (; j + 8 <= deg; j += 8) {
        int s0 = bp[j], s1 = bp[j + 4];
        const float4* h0 = (const float4*)(hin + (size_t)s0 * PAD);
        const float4* h1 = (const float4*)(hin + (size_t)s1 * PAD);
        float4 a0 = h0[0], e0 = h0[1], a1 = h1[0], e1 = h1[1];
        if (GDIS) {
            float d0 = dis[s0], d1 = dis[s1];
            acc[0] += a0.x * d0 + a1.x * d1;
            acc[1] += a0.y * d0 + a1.y * d1;
            acc[2] += a0.z * d0 + a1.z * d1;
            acc[3] += a0.w * d0 + a1.w * d1;
            acc[4] += e0.x * d0 + e1.x * d1;
        } else {
            acc[0] += a0.x + a1.x;
            acc[1] += a0.y + a1.y;
            acc[2] += a0.z + a1.z;
            acc[3] += a0.w + a1.w;
            acc[4] += e0.x + e1.x;
        }
    }
    for (; j < deg; j += 4) {
        int s0 = bp[j];
        const float4* h0 = (const float4*)(hin + (size_t)s0 * PAD);
        float4 a0 = h0[0], e0 = h0[1];
        if (GDIS) {
            float d0 = dis[s0];
            acc[0] += a0.x * d0;
            acc[1] += a0.y * d0;
            acc[2] += a0.z * d0;
            acc[3] += a0.w * d0;
            acc[4] += e0.x * d0;
        } else {
            acc[0] += a0.x;
            acc[1] += a0.y;
            acc[2] += a0.z;
            acc[3] += a0.w;
            acc[4] += e0.x;
        }
    }
#pragma unroll
    for (int c = 0; c < H; ++c) {
        acc[c] += __shfl_xor(acc[c], 1, 64);
        acc[c] += __shfl_xor(acc[c], 2, 64);
    }
    if (sub != 0) return;

    float di = dis[node];
    const float4* hp4 = (const float4*)(hin + (size_t)node * PAD);
    float4 ha = hp4[0];
    float h4 = hin[(size_t)node * PAD + 4];
    float hself[H] = {ha.x, ha.y, ha.z, ha.w, h4};
    float selfs = GDIS ? di * di : di;
    float tt[H];
#pragma unroll
    for (int c = 0; c < H; ++c) {
        float v = acc[c] * di + hself[c] * selfs + bn[c];
        tt[c] = v > 0.f ? v : 0.f;
    }
    float* op = outp + (size_t)node * OSTRIDE;
#pragma unroll
    for (int c2 = 0; c2 < OUTD; ++c2) {
        float a = ADD_B3 ? b3[c2] : 0.f;
#pragma unroll
        for (int c = 0; c < H; ++c) a += tt[c] * Wnext[c * OUTD + c2];
        op[c2] = SCALE_OUT ? a * di : a;
    }
}

extern "C" void kernel_launch(void* const* d_in, const int* in_sizes, int n_in,
                              void* d_out, int out_size, void* d_ws, size_t ws_size,
                              hipStream_t stream) {
    const float* x  = (const float*)d_in[0];
    const int*   ei = (const int*)d_in[1];
    const float* W1 = (const float*)d_in[2];
    const float* b1 = (const float*)d_in[3];
    const float* W2 = (const float*)d_in[4];
    const float* b2 = (const float*)d_in[5];
    const float* W3 = (const float*)d_in[6];
    const float* b3 = (const float*)d_in[7];
    float* out = (float*)d_out;

    const int n = in_sizes[0] / F_DIM;
    const int E = in_sizes[1] / 2;
    const int* src = ei;
    const int* dst = ei + E;
    const int np = (n + PART_NODES - 1) / PART_NODES;

    char* ws = (char*)d_ws;
    size_t off = 0;
    int* gcur = (int*)(ws + off);                   off += NPMAX * 4;
    unsigned int* parr = (unsigned int*)(ws + off); off += (size_t)np * PCAP * 4;
    int* sorted = (int*)(ws + off);                 off += (size_t)np * PCAP * 4;
    int* row_ptr = (int*)(ws + off);                off += (size_t)n * 4;
    int* degv = (int*)(ws + off);                   off += (size_t)n * 4;
    float* dis = (float*)(ws + off);                off += (size_t)n * 4;
    float* hw1 = (float*)(ws + off);                off += (size_t)n * PAD * 4;
    float* hw2 = (float*)(ws + off);                off += (size_t)n * PAD * 4;

    hipMemsetAsync(gcur, 0, NPMAX * sizeof(int), stream);

    const int npart_blocks = (E + TILE - 1) / TILE;
    const int XWB = 1852;                 // xw1 blocks (8 waves each)
    const int nb4 = (4 * n + 255) / 256;

    k_part<<<npart_blocks, 512, 0, stream>>>(src, dst, gcur, parr, E);
    k_csr_xw1<<<np + XWB, 512, 0, stream>>>(gcur, parr, sorted, row_ptr, degv, dis,
                                            x, W1, hw1, n, np);
    // layer1: raw h in hw1, gather dis[src]; write (t@W2)*dis[node] into hw2
    k_layer<H, PAD, false, true, true><<<nb4, 256, 0, stream>>>(
        sorted, row_ptr, degv, dis, hw1, b1, W2, nullptr, hw2, n);
    // layer2: hw2 already carries dis[src]; add b3, write logits
    k_layer<C, C, true, false, false><<<nb4, 256, 0, stream>>>(
        sorted, row_ptr, degv, dis, hw2, b2, W3, b3, out, n);
}